// Round 9
// baseline (309.894 us; speedup 1.0000x reference)
//
#include <hip/hip_runtime.h>
#include <math.h>

#define B_    256
#define C_    22
#define T_    1000
#define NB_   6
#define E_    6
#define MNB_  48
#define POOL_ 125
#define TP_   8
#define NC_   9
#define FEAT_ 384   // MNB_*TP_

#define PQ_   352    // plane length; x[m] lives at (plane (m+24)%3, q (m+24)/3)
#define NTH   768
#define CH_   11     // channels per half

// Load 4 aligned float4 (16 floats) from plane pp at element base 4*tile+Aoff.
#define LOADP(F, pp, Aoff)                                                   \
    {                                                                        \
        const float4* pb = (const float4*)&bw[pp][4*tile + (Aoff)];          \
        float4 q0 = pb[0], q1 = pb[1], q2 = pb[2], q3 = pb[3];               \
        *(float4*)&F[0]  = q0; *(float4*)&F[4]  = q1;                        \
        *(float4*)&F[8]  = q2; *(float4*)&F[12] = q3;                        \
    }

// Apply taps of BOTH nb of the pair to window F.
#define TAPS(F, idx0, j0, nj)                                                \
    _Pragma("unroll")                                                        \
    for (int a = 0; a < (nj); ++a) {                                         \
        const float ca = ckA[(j0) + 3*a];                                    \
        const float cb = ckB[(j0) + 3*a];                                    \
        sa0 = fmaf(ca, F[(idx0) + a    ], sa0);                              \
        sa1 = fmaf(ca, F[(idx0) + a + 1], sa1);                              \
        sa2 = fmaf(ca, F[(idx0) + a + 2], sa2);                              \
        sa3 = fmaf(ca, F[(idx0) + a + 3], sa3);                              \
        sb0 = fmaf(cb, F[(idx0) + a    ], sb0);                              \
        sb1 = fmaf(cb, F[(idx0) + a + 1], sb1);                              \
        sb2 = fmaf(cb, F[(idx0) + a + 2], sb2);                              \
        sb3 = fmaf(cb, F[(idx0) + a + 3], sb3);                              \
    }

// ---------------------------------------------------------------------------
// Fully fused kernel, channel-halved for 2 blocks/CU (R9):
//  - stage 11 channels at a time (planes 46.5 KB); LDS ~58 KB -> 2 blocks/CU
//    = 6 waves/SIMD (was 1 block, 3 waves/SIMD, latency-bound)
//  - hrow aliases the plane buffer (planes dead once both halves consumed)
//  - per half: stage -> phaseB (boundary FIR dots) -> phaseC (exact special
//    outputs) + barrier-free fused main loop; accs live across halves
// ---------------------------------------------------------------------------
__global__ __attribute__((amdgpu_waves_per_eu(6)))
__launch_bounds__(NTH) void fb_fused(
    const float* __restrict__ x,
    const float* __restrict__ fir,
    const float* __restrict__ w3,
    const float* __restrict__ w5,
    const float* __restrict__ w7,
    const float* __restrict__ bn_g, const float* __restrict__ bn_b,
    const float* __restrict__ bn_m, const float* __restrict__ bn_v,
    const float* __restrict__ sconv_w,
    const float* __restrict__ gate_w, const float* __restrict__ gate_b,
    const float* __restrict__ exp_w,  const float* __restrict__ exp_b,
    const float* __restrict__ ebn_g,  const float* __restrict__ ebn_b,
    const float* __restrict__ ebn_m,  const float* __restrict__ ebn_v,
    const float* __restrict__ fc_w,   const float* __restrict__ fc_b,
    float* __restrict__ feats_out, float* __restrict__ logp_out)
{
    const int b   = blockIdx.x;
    const int tid = threadIdx.x;

    __shared__ __align__(16) float pl[CH_][3][PQ_];  // 46.5 KB; hrow aliases
    __shared__ float firs6[NB_][21];
    __shared__ float w3s6[NB_][3];
    __shared__ float w5s6[NB_][5];
    __shared__ float w7s6[NB_][7];
    __shared__ float sws6[NB_][C_];
    __shared__ float sbn6[NB_][2];
    __shared__ float ckl[3][NB_][29];    // fused 29-tap kernels per (r, nb)
    __shared__ float xbv[NB_][CH_][13];  // xb(0..6), xb(994..999) per (nb,cl)
    __shared__ float term[NB_][6][C_];
    __shared__ float corr[NB_][6];
    __shared__ float psum[MNB_];
    __shared__ float hpl[MNB_];
    __shared__ float gms[NB_];
    __shared__ float lg[MNB_];
    __shared__ float gsh[E_];
    __shared__ float fsh[FEAT_];
    __shared__ float fpart[NC_][8];
    __shared__ float lo[NC_];

    float (*hrow)[T_] = (float (*)[T_])pl;   // alias: valid after final sync

    const float* xbase = x + (size_t)b * (C_ * T_);

    // ---- weights to LDS (once) ----
    if (tid < 126)                      { int nb=tid/21;  firs6[nb][tid%21] = fir[tid]; }
    else if (tid >= 128 && tid < 146)   { int k=tid-128;  w3s6[k/3][k%3] = w3[k]; }
    else if (tid >= 160 && tid < 190)   { int k=tid-160;  w5s6[k/5][k%5] = w5[k]; }
    else if (tid >= 192 && tid < 234)   { int k=tid-192;  w7s6[k/7][k%7] = w7[k]; }
    else if (tid >= 256 && tid < 388)   { int k=tid-256;  sws6[k/C_][k%C_] = sconv_w[k]; }
    else if (tid >= 400 && tid < 406) {
        const int nb = tid - 400;
        float sc = bn_g[nb] * rsqrtf(bn_v[nb] + 1e-5f);
        sbn6[nb][0] = sc * (1.f/3.f);          // folds the /3 of the triple-mean
        sbn6[nb][1] = bn_b[nb] - bn_m[nb] * sc;
    }

    // ---- wave-uniform region decomposition ----
    const int rr = tid >> 8;                 // region 0,1,2 — uniform per wave
    const int j  = tid & 255;
    int pair = 0, tile = 0;
    bool act = false;
    if (rr == 0)      { act = (j < 249); pair = j / 83; tile = j % 83; }
    else if (rr == 1) { act = (j < 252); pair = j / 84; tile = 83 + j % 84; }
    else              { act = (j < 249); pair = j / 83; tile = 167 + j % 83; }
    const int nb0 = 2 * pair, nb1 = nb0 + 1;

    float ckA[29], ckB[29];
    float scA = 0.f, biA = 0.f, scB = 0.f, biB = 0.f;
    float aA0 = 0.f, aA1 = 0.f, aA2 = 0.f, aA3 = 0.f;
    float aB0 = 0.f, aB1 = 0.f, aB2 = 0.f, aB3 = 0.f;

    #pragma unroll 1
    for (int h = 0; h < 2; ++h) {
        // ---- stage half h: 11 channels in plane order ----
        #pragma unroll
        for (int k = 0; k < 4; ++k) {
            const int idx = tid + k * NTH;            // 0..3071
            if (idx < CH_ * 264) {                    // 2904
                const int cl  = idx / 264;
                const int rem = idx % 264;
                const int p   = rem / 88;
                const int q0  = (rem % 88) * 4;
                const float* xr = xbase + (h * CH_ + cl) * T_;
                float v[4];
                #pragma unroll
                for (int i = 0; i < 4; ++i) {
                    const int m  = 3 * (q0 + i) + p - 24;
                    const int mc = m < 0 ? 0 : (m > 999 ? 999 : m);
                    const float val = xr[mc];
                    v[i] = ((unsigned)m < 1000u) ? val : 0.f;
                }
                *(float4*)&pl[cl][p][q0] = make_float4(v[0], v[1], v[2], v[3]);
            }
        }
        __syncthreads();   // S1: planes + (h==0) weights visible

        // ---- (h==0) build ckl ∥ phaseB: boundary FIR dots for this half ----
        if (h == 0 && tid < 522) {                    // 18 combos * 29 taps
            const int combo = tid / 29, jj = tid % 29;
            const int rr2 = combo / 6, nb = combo % 6;
            const float* wk = (rr2 == 0) ? w3s6[nb] : (rr2 == 1 ? w5s6[nb] : w7s6[nb]);
            const int K  = (rr2 == 0) ? 3 : (rr2 == 1 ? 5 : 7);
            const int pk = K >> 1;
            float s = 0.f;
            #pragma unroll
            for (int oi = 0; oi < 9; ++oi) {
                const int o = oi - 3;
                float we = 0.f;
                for (int k = 0; k < 7; ++k) {
                    if (k < K) {
                        const int jx = o + pk - k;
                        if (jx >= 0 && jx < 3) we += wk[k];
                    }
                }
                const int i = jj - oi;
                if (i >= 0 && i < 21) s = fmaf(we, firs6[nb][i], s);
            }
            ckl[rr2][nb][jj] = s;
        }
        for (int idx = tid; idx < NB_ * CH_ * 13; idx += NTH) {  // 858
            const int nb  = idx / (CH_ * 13);
            const int rem = idx % (CH_ * 13);
            const int cl  = rem / 13, pos = rem % 13;
            const int m   = (pos < 7) ? pos : (987 + pos);       // 0..6, 994..999
            int mm = m + 14;                                     // (m-10)+24
            int q  = mm / 3, p = mm - 3 * q;
            float s = 0.f;
            #pragma unroll
            for (int i = 0; i < 21; ++i) {
                s = fmaf(firs6[nb][i], pl[cl][p][q], s);
                ++p; if (p == 3) { p = 0; ++q; }
            }
            xbv[nb][cl][pos] = s;
        }
        __syncthreads();   // S2: xbv + (h==0) ckl visible

        // ---- phaseC: exact special outputs for this half's channels ----
        for (int idx = tid; idx < NB_ * 6 * CH_; idx += NTH) {   // 396
            const int nb  = idx / (6 * CH_);
            const int rem = idx % (6 * CH_);
            const int tix = rem / CH_, cl = rem % CH_;
            const float* X  = xbv[nb][cl];  // X[0..6]=xb(0..6), X[7..12]=xb(994..999)
            const float* W3 = w3s6[nb];
            const float* W5 = w5s6[nb];
            const float* W7 = w7s6[nb];
            float s;
            switch (tix) {
            case 0:
                s = W3[1]*X[0]+W3[2]*X[1]
                  + W3[0]*X[0]+W3[1]*X[1]+W3[2]*X[2]
                  + W3[0]*X[1]+W3[1]*X[2]+W3[2]*X[3];
                break;
            case 1:
                s = W3[0]*X[8]+W3[1]*X[9]+W3[2]*X[10]
                  + W3[0]*X[9]+W3[1]*X[10]+W3[2]*X[11]
                  + W3[0]*X[10]+W3[1]*X[11]+W3[2]*X[12];
                break;
            case 2:
                s = W3[0]*X[11]+W3[1]*X[12]
                  + W5[2]*X[0]+W5[3]*X[1]+W5[4]*X[2]
                  + W5[1]*X[0]+W5[2]*X[1]+W5[3]*X[2]+W5[4]*X[3];
                break;
            case 3:
                s = W5[0]*X[9]+W5[1]*X[10]+W5[2]*X[11]+W5[3]*X[12]
                  + W5[0]*X[10]+W5[1]*X[11]+W5[2]*X[12]
                  + W7[3]*X[0]+W7[4]*X[1]+W7[5]*X[2]+W7[6]*X[3];
                break;
            case 4:
                s = W7[2]*X[0]+W7[3]*X[1]+W7[4]*X[2]+W7[5]*X[3]+W7[6]*X[4]
                  + W7[1]*X[0]+W7[2]*X[1]+W7[3]*X[2]+W7[4]*X[3]+W7[5]*X[4]+W7[6]*X[5]
                  + W7[0]*X[0]+W7[1]*X[1]+W7[2]*X[2]+W7[3]*X[3]+W7[4]*X[4]+W7[5]*X[5]+W7[6]*X[6];
                break;
            default:
                s = W7[0]*X[7]+W7[1]*X[8]+W7[2]*X[9]+W7[3]*X[10]+W7[4]*X[11]+W7[5]*X[12]
                  + W7[0]*X[8]+W7[1]*X[9]+W7[2]*X[10]+W7[3]*X[11]+W7[4]*X[12]
                  + W7[0]*X[9]+W7[1]*X[10]+W7[2]*X[11]+W7[3]*X[12];
                break;
            }
            const float v = fmaxf(fmaf(s, sbn6[nb][0], sbn6[nb][1]), 0.f);
            term[nb][tix][h * CH_ + cl] = v * sws6[nb][h * CH_ + cl];
        }

        // ---- (h==0) gather per-thread taps + BN constants ----
        if (h == 0 && act) {
            #pragma unroll
            for (int t2 = 0; t2 < 29; ++t2) {
                ckA[t2] = ckl[rr][nb0][t2];
                ckB[t2] = ckl[rr][nb1][t2];
            }
            scA = sbn6[nb0][0]; biA = sbn6[nb0][1];
            scB = sbn6[nb1][0]; biB = sbn6[nb1][1];
        }

        // ---- main loop over this half's channels (barrier-free) ----
        if (act) {
            #pragma unroll 1
            for (int c = 0; c < CH_; ++c) {
                const float (*bw)[PQ_] = pl[c];
                float f0[16], f1[16], f2[16];
                float sa0 = 0.f, sa1 = 0.f, sa2 = 0.f, sa3 = 0.f;
                float sb0 = 0.f, sb1 = 0.f, sb2 = 0.f, sb3 = 0.f;
                if (rr == 0) {
                    LOADP(f0, 2, 0) LOADP(f1, 0, 4)
                    TAPS(f0, 3, 0, 10)
                    LOADP(f2, 1, 4)
                    TAPS(f1, 0, 1, 10) TAPS(f2, 0, 2, 9)
                } else if (rr == 1) {
                    LOADP(f0, 1, -332) LOADP(f1, 2, -332)
                    TAPS(f0, 2, 0, 10)
                    LOADP(f2, 0, -332)
                    TAPS(f1, 2, 1, 10) TAPS(f2, 3, 2, 9)
                } else {
                    LOADP(f0, 0, -664) LOADP(f1, 1, -664)
                    TAPS(f0, 1, 0, 10)
                    LOADP(f2, 2, -664)
                    TAPS(f1, 1, 1, 10) TAPS(f2, 1, 2, 9)
                }
                const int ch = h * CH_ + c;
                const float swA = sws6[nb0][ch], swB = sws6[nb1][ch];
                aA0 += fmaxf(fmaf(sa0, scA, biA), 0.f) * swA;
                aA1 += fmaxf(fmaf(sa1, scA, biA), 0.f) * swA;
                aA2 += fmaxf(fmaf(sa2, scA, biA), 0.f) * swA;
                aA3 += fmaxf(fmaf(sa3, scA, biA), 0.f) * swA;
                aB0 += fmaxf(fmaf(sb0, scB, biB), 0.f) * swB;
                aB1 += fmaxf(fmaf(sb1, scB, biB), 0.f) * swB;
                aB2 += fmaxf(fmaf(sb2, scB, biB), 0.f) * swB;
                aB3 += fmaxf(fmaf(sb3, scB, biB), 0.f) * swB;
            }
        }
        __syncthreads();   // S3: all pl reads done (next stage / hrow alias safe)
    }

    // ---- hrow writes (alias pl) + corr reduce ----
    if (act) {
        *(float4*)&hrow[nb0][4*tile] = make_float4(aA0, aA1, aA2, aA3);
        *(float4*)&hrow[nb1][4*tile] = make_float4(aB0, aB1, aB2, aB3);
    }
    if (tid < 36) {
        const int nb = tid / 6, tix = tid % 6;
        float s = 0.f;
        for (int c = 0; c < C_; ++c) s += term[nb][tix][c];
        corr[nb][tix] = s;
    }
    __syncthreads();
    if (tid < 36) {    // substitute exact special outputs
        const int nb = tid / 6, tix = tid % 6;
        const int t = (tix == 0) ? 0 :
                      (tix <= 2) ? (331 + tix) :        // 332, 333
                      (tix <= 4) ? (663 + tix) : 999;   // 666, 667
        hrow[nb][t] = corr[nb][tix];
    }
    __syncthreads();

    // ---- pooling: 48 windows x 8 threads ----
    if (tid < 384) {
        const int w = tid >> 3, jj = tid & 7;
        const int nb = w >> 3, p = w & 7;
        float s = 0.f;
        for (int k = jj; k < POOL_; k += 8) s += hrow[nb][p*POOL_ + k];
        s += __shfl_down(s, 4, 8);
        s += __shfl_down(s, 2, 8);
        s += __shfl_down(s, 1, 8);
        if (jj == 0) { psum[w] = s; hpl[w] = s * (1.f / POOL_); }
    }
    __syncthreads();
    if (tid < NB_) {
        float s = 0.f;
        for (int p = 0; p < TP_; ++p) s += psum[tid*TP_ + p];
        gms[tid] = s * (1.f / T_);
    }
    __syncthreads();

    // ---- stage2: gate logits ----
    if (tid < MNB_) {
        float s = gate_b[tid];
        for (int c = 0; c < NB_; ++c) s += gms[c] * gate_w[tid*NB_ + c];
        lg[tid] = s;
    }
    __syncthreads();
    if (tid == 0) {
        float mx = lg[0];
        for (int i = 1; i < MNB_; ++i) mx = fmaxf(mx, lg[i]);
        for (int i = 0; i < MNB_; ++i) lg[i] = expf(lg[i] - mx);
        int i1 = 0, i2 = -1, i3 = -1;
        float b1 = -1.f, b2 = -1.f, b3 = -1.f;
        for (int i = 0; i < MNB_; ++i) if (lg[i] > b1) { b1 = lg[i]; i1 = i; }
        for (int i = 0; i < MNB_; ++i) if (i != i1 && lg[i] > b2) { b2 = lg[i]; i2 = i; }
        for (int i = 0; i < MNB_; ++i) if (i != i1 && i != i2 && lg[i] > b3) { b3 = lg[i]; i3 = i; }
        const float s3 = lg[i1] + lg[i2] + lg[i3];
        for (int jj = 0; jj < E_; ++jj) gsh[jj] = 0.f;
        if (i1 < E_) gsh[i1] = lg[i1] / s3;
        if (i2 < E_) gsh[i2] = lg[i2] / s3;
        if (i3 < E_) gsh[i3] = lg[i3] / s3;
    }
    __syncthreads();

    // ---- experts + EBN + ReLU + gate-mix -> feats ----
    if (tid < FEAT_) {
        const int o = tid >> 3, p = tid & 7;
        float outv = 0.f;
        #pragma unroll
        for (int e = 0; e < E_; ++e) {
            const int eo = e*MNB_ + o;
            float acc = exp_b[eo];
            #pragma unroll
            for (int c = 0; c < NB_; ++c)
                acc += hpl[c*TP_ + p] * exp_w[eo*NB_ + c];
            const float esc = ebn_g[eo] * rsqrtf(ebn_v[eo] + 1e-5f);
            float v = fmaf(acc - ebn_m[eo], esc, ebn_b[eo]);
            v = fmaxf(v, 0.f);
            outv += gsh[e] * v;
        }
        fsh[tid] = outv;
        feats_out[b*FEAT_ + tid] = outv;
    }
    __syncthreads();

    // ---- FC: 9 classes x 8 partials ----
    if (tid < NC_ * 8) {
        const int cls = tid >> 3, part = tid & 7;
        float s = 0.f;
        const float* wr = fc_w + cls*FEAT_ + part*48;
        const float* fr = fsh + part*48;
        for (int i = 0; i < 48; ++i) s = fmaf(fr[i], wr[i], s);
        fpart[cls][part] = s;
    }
    __syncthreads();
    if (tid < NC_) {
        float s = fc_b[tid];
        for (int p = 0; p < 8; ++p) s += fpart[tid][p];
        lo[tid] = s;
    }
    __syncthreads();
    if (tid == 0) {
        float mx = lo[0];
        for (int k = 1; k < NC_; ++k) mx = fmaxf(mx, lo[k]);
        float Z = 0.f;
        for (int k = 0; k < NC_; ++k) Z += expf(lo[k] - mx);
        const float lse = mx + logf(Z);
        for (int k = 0; k < NC_; ++k) logp_out[b*NC_ + k] = lo[k] - lse;
    }
}

extern "C" void kernel_launch(void* const* d_in, const int* in_sizes, int n_in,
                              void* d_out, int out_size, void* d_ws, size_t ws_size,
                              hipStream_t stream) {
    const float* x       = (const float*)d_in[0];
    const float* fir     = (const float*)d_in[1];
    const float* w3      = (const float*)d_in[2];
    const float* w5      = (const float*)d_in[3];
    const float* w7      = (const float*)d_in[4];
    const float* bn1_g   = (const float*)d_in[5];
    const float* bn1_b   = (const float*)d_in[6];
    const float* bn1_m   = (const float*)d_in[7];
    const float* bn1_v   = (const float*)d_in[8];
    const float* sconv_w = (const float*)d_in[9];
    const float* gate_w  = (const float*)d_in[10];
    const float* gate_b  = (const float*)d_in[11];
    const float* exp_w   = (const float*)d_in[12];
    const float* exp_b   = (const float*)d_in[13];
    const float* ebn_g   = (const float*)d_in[14];
    const float* ebn_b   = (const float*)d_in[15];
    const float* ebn_m   = (const float*)d_in[16];
    const float* ebn_v   = (const float*)d_in[17];
    const float* fc_w    = (const float*)d_in[18];
    const float* fc_b    = (const float*)d_in[19];

    float* out       = (float*)d_out;
    float* feats_out = out;                     // (256, 384)
    float* logp_out  = out + B_ * FEAT_;        // (256, 9)

    fb_fused<<<B_, NTH, 0, stream>>>(x, fir, w3, w5, w7,
                                     bn1_g, bn1_b, bn1_m, bn1_v, sconv_w,
                                     gate_w, gate_b, exp_w, exp_b,
                                     ebn_g, ebn_b, ebn_m, ebn_v,
                                     fc_w, fc_b, feats_out, logp_out);
}

// Round 10
// 100.033 us; speedup vs baseline: 3.0979x; 3.0979x over previous
//
#include <hip/hip_runtime.h>
#include <math.h>

#define B_    256
#define C_    22
#define T_    1000
#define NB_   6
#define E_    6
#define MNB_  48
#define POOL_ 125
#define TP_   8
#define NC_   9
#define FEAT_ 384   // MNB_*TP_

#define PQ_   352    // plane length; x[m] lives at (plane (m+24)%3, q (m+24)/3)
#define NTH   768
#define CH_   11     // channels per half

// Load 4 aligned float4 (16 floats) from plane pp at element base 4*tile+Aoff.
#define LOADP(F, pp, Aoff)                                                   \
    {                                                                        \
        const float4* pb = (const float4*)&bw[pp][4*tile + (Aoff)];          \
        float4 q0 = pb[0], q1 = pb[1], q2 = pb[2], q3 = pb[3];               \
        *(float4*)&F[0]  = q0; *(float4*)&F[4]  = q1;                        \
        *(float4*)&F[8]  = q2; *(float4*)&F[12] = q3;                        \
    }

// Apply taps of BOTH nb of the pair to window F.
#define TAPS(F, idx0, j0, nj)                                                \
    _Pragma("unroll")                                                        \
    for (int a = 0; a < (nj); ++a) {                                         \
        const float ca = ckA[(j0) + 3*a];                                    \
        const float cb = ckB[(j0) + 3*a];                                    \
        sa0 = fmaf(ca, F[(idx0) + a    ], sa0);                              \
        sa1 = fmaf(ca, F[(idx0) + a + 1], sa1);                              \
        sa2 = fmaf(ca, F[(idx0) + a + 2], sa2);                              \
        sa3 = fmaf(ca, F[(idx0) + a + 3], sa3);                              \
        sb0 = fmaf(cb, F[(idx0) + a    ], sb0);                              \
        sb1 = fmaf(cb, F[(idx0) + a + 1], sb1);                              \
        sb2 = fmaf(cb, F[(idx0) + a + 2], sb2);                              \
        sb3 = fmaf(cb, F[(idx0) + a + 3], sb3);                              \
    }

// ---------------------------------------------------------------------------
// Fully fused kernel, channel-halved staging (R10):
//  __launch_bounds__(NTH, 1): VGPR cap 256 so the ~140-reg main loop
//  (ckA/ckB 58 + windows + accs) allocates WITHOUT spill. History:
//  (768,3)->cap 84, ~10-dword spill, 8 MB scratch (R7/R8);
//  waves_per_eu(6)->cap 40, ck arrays spilled, 1 GB scratch (R9).
//  LDS 59 KB; 1 block/CU (12 waves, 3/SIMD) as long as VGPR <= 170.
// ---------------------------------------------------------------------------
__global__ __launch_bounds__(NTH, 1) void fb_fused(
    const float* __restrict__ x,
    const float* __restrict__ fir,
    const float* __restrict__ w3,
    const float* __restrict__ w5,
    const float* __restrict__ w7,
    const float* __restrict__ bn_g, const float* __restrict__ bn_b,
    const float* __restrict__ bn_m, const float* __restrict__ bn_v,
    const float* __restrict__ sconv_w,
    const float* __restrict__ gate_w, const float* __restrict__ gate_b,
    const float* __restrict__ exp_w,  const float* __restrict__ exp_b,
    const float* __restrict__ ebn_g,  const float* __restrict__ ebn_b,
    const float* __restrict__ ebn_m,  const float* __restrict__ ebn_v,
    const float* __restrict__ fc_w,   const float* __restrict__ fc_b,
    float* __restrict__ feats_out, float* __restrict__ logp_out)
{
    const int b   = blockIdx.x;
    const int tid = threadIdx.x;

    __shared__ __align__(16) float pl[CH_][3][PQ_];  // 46.5 KB; hrow aliases
    __shared__ float firs6[NB_][21];
    __shared__ float w3s6[NB_][3];
    __shared__ float w5s6[NB_][5];
    __shared__ float w7s6[NB_][7];
    __shared__ float sws6[NB_][C_];
    __shared__ float sbn6[NB_][2];
    __shared__ float ckl[3][NB_][29];    // fused 29-tap kernels per (r, nb)
    __shared__ float xbv[NB_][CH_][13];  // xb(0..6), xb(994..999) per (nb,cl)
    __shared__ float term[NB_][6][C_];
    __shared__ float corr[NB_][6];
    __shared__ float psum[MNB_];
    __shared__ float hpl[MNB_];
    __shared__ float gms[NB_];
    __shared__ float lg[MNB_];
    __shared__ float gsh[E_];
    __shared__ float fsh[FEAT_];
    __shared__ float fpart[NC_][8];
    __shared__ float lo[NC_];

    float (*hrow)[T_] = (float (*)[T_])pl;   // alias: valid after final sync

    const float* xbase = x + (size_t)b * (C_ * T_);

    // ---- weights to LDS (once) ----
    if (tid < 126)                      { int nb=tid/21;  firs6[nb][tid%21] = fir[tid]; }
    else if (tid >= 128 && tid < 146)   { int k=tid-128;  w3s6[k/3][k%3] = w3[k]; }
    else if (tid >= 160 && tid < 190)   { int k=tid-160;  w5s6[k/5][k%5] = w5[k]; }
    else if (tid >= 192 && tid < 234)   { int k=tid-192;  w7s6[k/7][k%7] = w7[k]; }
    else if (tid >= 256 && tid < 388)   { int k=tid-256;  sws6[k/C_][k%C_] = sconv_w[k]; }
    else if (tid >= 400 && tid < 406) {
        const int nb = tid - 400;
        float sc = bn_g[nb] * rsqrtf(bn_v[nb] + 1e-5f);
        sbn6[nb][0] = sc * (1.f/3.f);          // folds the /3 of the triple-mean
        sbn6[nb][1] = bn_b[nb] - bn_m[nb] * sc;
    }

    // ---- wave-uniform region decomposition ----
    const int rr = tid >> 8;                 // region 0,1,2 — uniform per wave
    const int j  = tid & 255;
    int pair = 0, tile = 0;
    bool act = false;
    if (rr == 0)      { act = (j < 249); pair = j / 83; tile = j % 83; }
    else if (rr == 1) { act = (j < 252); pair = j / 84; tile = 83 + j % 84; }
    else              { act = (j < 249); pair = j / 83; tile = 167 + j % 83; }
    const int nb0 = 2 * pair, nb1 = nb0 + 1;

    float ckA[29], ckB[29];
    float scA = 0.f, biA = 0.f, scB = 0.f, biB = 0.f;
    float aA0 = 0.f, aA1 = 0.f, aA2 = 0.f, aA3 = 0.f;
    float aB0 = 0.f, aB1 = 0.f, aB2 = 0.f, aB3 = 0.f;

    #pragma unroll 1
    for (int h = 0; h < 2; ++h) {
        // ---- stage half h: 11 channels in plane order ----
        #pragma unroll
        for (int k = 0; k < 4; ++k) {
            const int idx = tid + k * NTH;            // 0..3071
            if (idx < CH_ * 264) {                    // 2904
                const int cl  = idx / 264;
                const int rem = idx % 264;
                const int p   = rem / 88;
                const int q0  = (rem % 88) * 4;
                const float* xr = xbase + (h * CH_ + cl) * T_;
                float v[4];
                #pragma unroll
                for (int i = 0; i < 4; ++i) {
                    const int m  = 3 * (q0 + i) + p - 24;
                    const int mc = m < 0 ? 0 : (m > 999 ? 999 : m);
                    const float val = xr[mc];
                    v[i] = ((unsigned)m < 1000u) ? val : 0.f;
                }
                *(float4*)&pl[cl][p][q0] = make_float4(v[0], v[1], v[2], v[3]);
            }
        }
        __syncthreads();   // S1: planes + (h==0) weights visible

        // ---- (h==0) build ckl ∥ phaseB: boundary FIR dots for this half ----
        if (h == 0 && tid < 522) {                    // 18 combos * 29 taps
            const int combo = tid / 29, jj = tid % 29;
            const int rr2 = combo / 6, nb = combo % 6;
            const float* wk = (rr2 == 0) ? w3s6[nb] : (rr2 == 1 ? w5s6[nb] : w7s6[nb]);
            const int K  = (rr2 == 0) ? 3 : (rr2 == 1 ? 5 : 7);
            const int pk = K >> 1;
            float s = 0.f;
            #pragma unroll
            for (int oi = 0; oi < 9; ++oi) {
                const int o = oi - 3;
                float we = 0.f;
                for (int k = 0; k < 7; ++k) {
                    if (k < K) {
                        const int jx = o + pk - k;
                        if (jx >= 0 && jx < 3) we += wk[k];
                    }
                }
                const int i = jj - oi;
                if (i >= 0 && i < 21) s = fmaf(we, firs6[nb][i], s);
            }
            ckl[rr2][nb][jj] = s;
        }
        for (int idx = tid; idx < NB_ * CH_ * 13; idx += NTH) {  // 858
            const int nb  = idx / (CH_ * 13);
            const int rem = idx % (CH_ * 13);
            const int cl  = rem / 13, pos = rem % 13;
            const int m   = (pos < 7) ? pos : (987 + pos);       // 0..6, 994..999
            int mm = m + 14;                                     // (m-10)+24
            int q  = mm / 3, p = mm - 3 * q;
            float s = 0.f;
            #pragma unroll
            for (int i = 0; i < 21; ++i) {
                s = fmaf(firs6[nb][i], pl[cl][p][q], s);
                ++p; if (p == 3) { p = 0; ++q; }
            }
            xbv[nb][cl][pos] = s;
        }
        __syncthreads();   // S2: xbv + (h==0) ckl visible

        // ---- phaseC: exact special outputs for this half's channels ----
        for (int idx = tid; idx < NB_ * 6 * CH_; idx += NTH) {   // 396
            const int nb  = idx / (6 * CH_);
            const int rem = idx % (6 * CH_);
            const int tix = rem / CH_, cl = rem % CH_;
            const float* X  = xbv[nb][cl];  // X[0..6]=xb(0..6), X[7..12]=xb(994..999)
            const float* W3 = w3s6[nb];
            const float* W5 = w5s6[nb];
            const float* W7 = w7s6[nb];
            float s;
            switch (tix) {
            case 0:
                s = W3[1]*X[0]+W3[2]*X[1]
                  + W3[0]*X[0]+W3[1]*X[1]+W3[2]*X[2]
                  + W3[0]*X[1]+W3[1]*X[2]+W3[2]*X[3];
                break;
            case 1:
                s = W3[0]*X[8]+W3[1]*X[9]+W3[2]*X[10]
                  + W3[0]*X[9]+W3[1]*X[10]+W3[2]*X[11]
                  + W3[0]*X[10]+W3[1]*X[11]+W3[2]*X[12];
                break;
            case 2:
                s = W3[0]*X[11]+W3[1]*X[12]
                  + W5[2]*X[0]+W5[3]*X[1]+W5[4]*X[2]
                  + W5[1]*X[0]+W5[2]*X[1]+W5[3]*X[2]+W5[4]*X[3];
                break;
            case 3:
                s = W5[0]*X[9]+W5[1]*X[10]+W5[2]*X[11]+W5[3]*X[12]
                  + W5[0]*X[10]+W5[1]*X[11]+W5[2]*X[12]
                  + W7[3]*X[0]+W7[4]*X[1]+W7[5]*X[2]+W7[6]*X[3];
                break;
            case 4:
                s = W7[2]*X[0]+W7[3]*X[1]+W7[4]*X[2]+W7[5]*X[3]+W7[6]*X[4]
                  + W7[1]*X[0]+W7[2]*X[1]+W7[3]*X[2]+W7[4]*X[3]+W7[5]*X[4]+W7[6]*X[5]
                  + W7[0]*X[0]+W7[1]*X[1]+W7[2]*X[2]+W7[3]*X[3]+W7[4]*X[4]+W7[5]*X[5]+W7[6]*X[6];
                break;
            default:
                s = W7[0]*X[7]+W7[1]*X[8]+W7[2]*X[9]+W7[3]*X[10]+W7[4]*X[11]+W7[5]*X[12]
                  + W7[0]*X[8]+W7[1]*X[9]+W7[2]*X[10]+W7[3]*X[11]+W7[4]*X[12]
                  + W7[0]*X[9]+W7[1]*X[10]+W7[2]*X[11]+W7[3]*X[12];
                break;
            }
            const float v = fmaxf(fmaf(s, sbn6[nb][0], sbn6[nb][1]), 0.f);
            term[nb][tix][h * CH_ + cl] = v * sws6[nb][h * CH_ + cl];
        }

        // ---- (h==0) gather per-thread taps + BN constants ----
        if (h == 0 && act) {
            #pragma unroll
            for (int t2 = 0; t2 < 29; ++t2) {
                ckA[t2] = ckl[rr][nb0][t2];
                ckB[t2] = ckl[rr][nb1][t2];
            }
            scA = sbn6[nb0][0]; biA = sbn6[nb0][1];
            scB = sbn6[nb1][0]; biB = sbn6[nb1][1];
        }

        // ---- main loop over this half's channels (barrier-free) ----
        if (act) {
            #pragma unroll 1
            for (int c = 0; c < CH_; ++c) {
                const float (*bw)[PQ_] = pl[c];
                float f0[16], f1[16], f2[16];
                float sa0 = 0.f, sa1 = 0.f, sa2 = 0.f, sa3 = 0.f;
                float sb0 = 0.f, sb1 = 0.f, sb2 = 0.f, sb3 = 0.f;
                if (rr == 0) {
                    LOADP(f0, 2, 0) LOADP(f1, 0, 4)
                    TAPS(f0, 3, 0, 10)
                    LOADP(f2, 1, 4)
                    TAPS(f1, 0, 1, 10) TAPS(f2, 0, 2, 9)
                } else if (rr == 1) {
                    LOADP(f0, 1, -332) LOADP(f1, 2, -332)
                    TAPS(f0, 2, 0, 10)
                    LOADP(f2, 0, -332)
                    TAPS(f1, 2, 1, 10) TAPS(f2, 3, 2, 9)
                } else {
                    LOADP(f0, 0, -664) LOADP(f1, 1, -664)
                    TAPS(f0, 1, 0, 10)
                    LOADP(f2, 2, -664)
                    TAPS(f1, 1, 1, 10) TAPS(f2, 1, 2, 9)
                }
                const int ch = h * CH_ + c;
                const float swA = sws6[nb0][ch], swB = sws6[nb1][ch];
                aA0 += fmaxf(fmaf(sa0, scA, biA), 0.f) * swA;
                aA1 += fmaxf(fmaf(sa1, scA, biA), 0.f) * swA;
                aA2 += fmaxf(fmaf(sa2, scA, biA), 0.f) * swA;
                aA3 += fmaxf(fmaf(sa3, scA, biA), 0.f) * swA;
                aB0 += fmaxf(fmaf(sb0, scB, biB), 0.f) * swB;
                aB1 += fmaxf(fmaf(sb1, scB, biB), 0.f) * swB;
                aB2 += fmaxf(fmaf(sb2, scB, biB), 0.f) * swB;
                aB3 += fmaxf(fmaf(sb3, scB, biB), 0.f) * swB;
            }
        }
        __syncthreads();   // S3: all pl reads done (next stage / hrow alias safe)
    }

    // ---- hrow writes (alias pl) + corr reduce ----
    if (act) {
        *(float4*)&hrow[nb0][4*tile] = make_float4(aA0, aA1, aA2, aA3);
        *(float4*)&hrow[nb1][4*tile] = make_float4(aB0, aB1, aB2, aB3);
    }
    if (tid < 36) {
        const int nb = tid / 6, tix = tid % 6;
        float s = 0.f;
        for (int c = 0; c < C_; ++c) s += term[nb][tix][c];
        corr[nb][tix] = s;
    }
    __syncthreads();
    if (tid < 36) {    // substitute exact special outputs
        const int nb = tid / 6, tix = tid % 6;
        const int t = (tix == 0) ? 0 :
                      (tix <= 2) ? (331 + tix) :        // 332, 333
                      (tix <= 4) ? (663 + tix) : 999;   // 666, 667
        hrow[nb][t] = corr[nb][tix];
    }
    __syncthreads();

    // ---- pooling: 48 windows x 8 threads ----
    if (tid < 384) {
        const int w = tid >> 3, jj = tid & 7;
        const int nb = w >> 3, p = w & 7;
        float s = 0.f;
        for (int k = jj; k < POOL_; k += 8) s += hrow[nb][p*POOL_ + k];
        s += __shfl_down(s, 4, 8);
        s += __shfl_down(s, 2, 8);
        s += __shfl_down(s, 1, 8);
        if (jj == 0) { psum[w] = s; hpl[w] = s * (1.f / POOL_); }
    }
    __syncthreads();
    if (tid < NB_) {
        float s = 0.f;
        for (int p = 0; p < TP_; ++p) s += psum[tid*TP_ + p];
        gms[tid] = s * (1.f / T_);
    }
    __syncthreads();

    // ---- stage2: gate logits ----
    if (tid < MNB_) {
        float s = gate_b[tid];
        for (int c = 0; c < NB_; ++c) s += gms[c] * gate_w[tid*NB_ + c];
        lg[tid] = s;
    }
    __syncthreads();
    if (tid == 0) {
        float mx = lg[0];
        for (int i = 1; i < MNB_; ++i) mx = fmaxf(mx, lg[i]);
        for (int i = 0; i < MNB_; ++i) lg[i] = expf(lg[i] - mx);
        int i1 = 0, i2 = -1, i3 = -1;
        float b1 = -1.f, b2 = -1.f, b3 = -1.f;
        for (int i = 0; i < MNB_; ++i) if (lg[i] > b1) { b1 = lg[i]; i1 = i; }
        for (int i = 0; i < MNB_; ++i) if (i != i1 && lg[i] > b2) { b2 = lg[i]; i2 = i; }
        for (int i = 0; i < MNB_; ++i) if (i != i1 && i != i2 && lg[i] > b3) { b3 = lg[i]; i3 = i; }
        const float s3 = lg[i1] + lg[i2] + lg[i3];
        for (int jj = 0; jj < E_; ++jj) gsh[jj] = 0.f;
        if (i1 < E_) gsh[i1] = lg[i1] / s3;
        if (i2 < E_) gsh[i2] = lg[i2] / s3;
        if (i3 < E_) gsh[i3] = lg[i3] / s3;
    }
    __syncthreads();

    // ---- experts + EBN + ReLU + gate-mix -> feats ----
    if (tid < FEAT_) {
        const int o = tid >> 3, p = tid & 7;
        float outv = 0.f;
        #pragma unroll
        for (int e = 0; e < E_; ++e) {
            const int eo = e*MNB_ + o;
            float acc = exp_b[eo];
            #pragma unroll
            for (int c = 0; c < NB_; ++c)
                acc += hpl[c*TP_ + p] * exp_w[eo*NB_ + c];
            const float esc = ebn_g[eo] * rsqrtf(ebn_v[eo] + 1e-5f);
            float v = fmaf(acc - ebn_m[eo], esc, ebn_b[eo]);
            v = fmaxf(v, 0.f);
            outv += gsh[e] * v;
        }
        fsh[tid] = outv;
        feats_out[b*FEAT_ + tid] = outv;
    }
    __syncthreads();

    // ---- FC: 9 classes x 8 partials ----
    if (tid < NC_ * 8) {
        const int cls = tid >> 3, part = tid & 7;
        float s = 0.f;
        const float* wr = fc_w + cls*FEAT_ + part*48;
        const float* fr = fsh + part*48;
        for (int i = 0; i < 48; ++i) s = fmaf(fr[i], wr[i], s);
        fpart[cls][part] = s;
    }
    __syncthreads();
    if (tid < NC_) {
        float s = fc_b[tid];
        for (int p = 0; p < 8; ++p) s += fpart[tid][p];
        lo[tid] = s;
    }
    __syncthreads();
    if (tid == 0) {
        float mx = lo[0];
        for (int k = 1; k < NC_; ++k) mx = fmaxf(mx, lo[k]);
        float Z = 0.f;
        for (int k = 0; k < NC_; ++k) Z += expf(lo[k] - mx);
        const float lse = mx + logf(Z);
        for (int k = 0; k < NC_; ++k) logp_out[b*NC_ + k] = lo[k] - lse;
    }
}

extern "C" void kernel_launch(void* const* d_in, const int* in_sizes, int n_in,
                              void* d_out, int out_size, void* d_ws, size_t ws_size,
                              hipStream_t stream) {
    const float* x       = (const float*)d_in[0];
    const float* fir     = (const float*)d_in[1];
    const float* w3      = (const float*)d_in[2];
    const float* w5      = (const float*)d_in[3];
    const float* w7      = (const float*)d_in[4];
    const float* bn1_g   = (const float*)d_in[5];
    const float* bn1_b   = (const float*)d_in[6];
    const float* bn1_m   = (const float*)d_in[7];
    const float* bn1_v   = (const float*)d_in[8];
    const float* sconv_w = (const float*)d_in[9];
    const float* gate_w  = (const float*)d_in[10];
    const float* gate_b  = (const float*)d_in[11];
    const float* exp_w   = (const float*)d_in[12];
    const float* exp_b   = (const float*)d_in[13];
    const float* ebn_g   = (const float*)d_in[14];
    const float* ebn_b   = (const float*)d_in[15];
    const float* ebn_m   = (const float*)d_in[16];
    const float* ebn_v   = (const float*)d_in[17];
    const float* fc_w    = (const float*)d_in[18];
    const float* fc_b    = (const float*)d_in[19];

    float* out       = (float*)d_out;
    float* feats_out = out;                     // (256, 384)
    float* logp_out  = out + B_ * FEAT_;        // (256, 9)

    fb_fused<<<B_, NTH, 0, stream>>>(x, fir, w3, w5, w7,
                                     bn1_g, bn1_b, bn1_m, bn1_v, sconv_w,
                                     gate_w, gate_b, exp_w, exp_b,
                                     ebn_g, ebn_b, ebn_m, ebn_v,
                                     fc_w, fc_b, feats_out, logp_out);
}